// Round 8
// baseline (16908.977 us; speedup 1.0000x reference)
//
#include <hip/hip_runtime.h>
#include <math.h>

#define BB 512     // batch
#define HH 1024    // hidden
#define OO 512     // output
#define KC 1536    // O + H
#define G4H 4096   // 4*H
#define TT 256     // out_len

typedef _Float16 half8 __attribute__((ext_vector_type(8)));
typedef _Float16 half4 __attribute__((ext_vector_type(4)));
typedef float f32x4 __attribute__((ext_vector_type(4)));

// ---------------------------------------------------------------------------
// Prep: Wcat f16 gate-interleaved (row-major [p][KC]), 32-granular permutation
// (proven): p -> jr = p&31, g = (p>>5)&3, jt = p>>7, n = g*HH+jt*32+jr.
// Wout16 row-major [O][H].
// ---------------------------------------------------------------------------
__global__ __launch_bounds__(256) void conv_wcat(
    const float* __restrict__ W_ih, const float* __restrict__ W_hh,
    _Float16* __restrict__ Wcat)
{
    int k = blockIdx.x * 256 + threadIdx.x;
    int p = blockIdx.y;
    int g = (p >> 5) & 3, jt = p >> 7, jr = p & 31;
    int n = g * HH + jt * 32 + jr;
    float v = (k < OO) ? W_ih[(size_t)n * OO + k] : W_hh[(size_t)n * HH + (k - OO)];
    Wcat[(size_t)p * KC + k] = (_Float16)v;
}

__global__ __launch_bounds__(256) void conv_wout(
    const float* __restrict__ W_out, _Float16* __restrict__ Wout16)
{
    int k = blockIdx.x * 256 + threadIdx.x;  // 0..1023
    int o = blockIdx.y;                      // 0..511
    Wout16[(size_t)o * HH + k] = (_Float16)W_out[(size_t)o * HH + k];
}

__global__ __launch_bounds__(256) void prep_misc(
    const float* __restrict__ b_ih, const float* __restrict__ b_hh,
    const float* __restrict__ h0, const float* __restrict__ c0,
    float* __restrict__ bias_p, _Float16* __restrict__ hb0, float* __restrict__ cst)
{
    int idx0 = blockIdx.x * blockDim.x + threadIdx.x;
    int stride = gridDim.x * blockDim.x;
    for (int p = idx0; p < G4H; p += stride) {
        int g = (p >> 5) & 3, jt = p >> 7, jr = p & 31;
        int n = g * HH + jt * 32 + jr;
        bias_p[p] = b_ih[n] + b_hh[n];
    }
    for (int i = idx0; i < BB * HH; i += stride) {
        hb0[i] = (_Float16)h0[i];
        cst[i] = c0[i];
    }
}

// ---------------------------------------------------------------------------
// gates_sf2: DIRECT-TO-REGISTER fragment GEMM. 64b x 128p per block,
// 512 threads = 8 waves (2 batch x 4 p), each wave 32b x 32p (fm=2, fn=2).
// MFMA fragment rows/chunks are loaded straight from global (row l15,
// 16B chunk ks*4+l4) — identical operand content to the old LDS path
// (swizzle algebra verified: cc^(R&7) with cc=(ks*4+l4)^(l&7), R&7=l&7),
// so accumulation is bitwise unchanged. NO LDS / NO barriers in the K-loop;
// 2 waves/SIMD hide L2 latency. Softmax consumption as in R7 (ebuf/Spart).
// ---------------------------------------------------------------------------
__global__ __launch_bounds__(512) void gates_sf2(
    const float* __restrict__ ebuf,       // [B][O] exp(logits) of step t-1
    const float* __restrict__ Spart,      // [B][32] partial sums
    const _Float16* __restrict__ h_in,    // [B][H]
    _Float16* __restrict__ h_out,         // [B][H]
    float* __restrict__ cst,              // [B][H]
    const _Float16* __restrict__ Wcat,    // [4096][KC] permuted
    const float* __restrict__ bias_p,     // [4096] permuted
    float* __restrict__ out_slice,        // out slice for step t-1
    int first)
{
    const int pt = blockIdx.x;
    const int p0 = pt * 128, b0 = blockIdx.y * 64;
    const int tid = threadIdx.x;
    const int l = tid & 63, w = tid >> 6;    // 8 waves
    const int wm = w & 1, wn = w >> 1;       // 2(b) x 4(p)
    const int l15 = l & 15, l4 = l >> 4;

    __shared__ __align__(16) char smem[34560];
    float* exch   = (float*)smem;            // [64][133] f32 (34048 B), epilogue only
    float* sm_inv = (float*)(smem + 34048);  // [64]

    // ---- prologue: 1/rowsum + this block's 2 out rows ----------------------
    if (!first) {
        if (tid < 64) {
            const float* sp = &Spart[(size_t)(b0 + tid) * 32];
            float s = 0.f;
            #pragma unroll
            for (int u = 0; u < 32; ++u) s += sp[u];
            sm_inv[tid] = 1.f / s;
        }
        __syncthreads();
        if (tid < 256) {
            int bl = pt * 2 + (tid >> 7);
            int col = (tid & 127) * 4;
            float inv = sm_inv[bl];
            float4 e4 = *(const float4*)&ebuf[(size_t)(b0 + bl) * OO + col];
            float4 y4 = {e4.x * inv, e4.y * inv, e4.z * inv, e4.w * inv};
            *(float4*)&out_slice[(size_t)(b0 + bl) * OO + col] = y4;
        }
    }
    __syncthreads();

    f32x4 acc[2][2];
    #pragma unroll
    for (int fm = 0; fm < 2; ++fm)
        #pragma unroll
        for (int fn = 0; fn < 2; ++fn)
            acc[fm][fn] = (f32x4){0.f, 0.f, 0.f, 0.f};

    // fragment base pointers (lane-resolved): row = base + l15, chunk = l4
    const int rA0 = wm * 32 + l15, rA1 = wm * 32 + 16 + l15;
    const float*    pE0 = &ebuf[(size_t)(b0 + rA0) * OO + l4 * 8];
    const float*    pE1 = &ebuf[(size_t)(b0 + rA1) * OO + l4 * 8];
    const _Float16* pH0 = &h_in[(size_t)(b0 + rA0) * HH + l4 * 8];
    const _Float16* pH1 = &h_in[(size_t)(b0 + rA1) * HH + l4 * 8];
    const _Float16* pB0 = &Wcat[(size_t)(p0 + wn * 32 +      l15) * KC + l4 * 8];
    const _Float16* pB1 = &Wcat[(size_t)(p0 + wn * 32 + 16 + l15) * KC + l4 * 8];
    const float invA0 = sm_inv[rA0];
    const float invA1 = sm_inv[rA1];

    // ---- x-part: K = 0..512 (4 iterations), skipped at t=0 (x=0) -----------
    if (!first) {
        const float* e0 = pE0;
        const float* e1 = pE1;
        const _Float16* wb0 = pB0;
        const _Float16* wb1 = pB1;
        #pragma unroll 1
        for (int it = 0; it < 4; ++it) {
            #pragma unroll
            for (int ks = 0; ks < 4; ++ks) {
                float lv0[8], lv1[8];
                *(float4*)&lv0[0] = *(const float4*)(e0 + ks * 32);
                *(float4*)&lv0[4] = *(const float4*)(e0 + ks * 32 + 4);
                *(float4*)&lv1[0] = *(const float4*)(e1 + ks * 32);
                *(float4*)&lv1[4] = *(const float4*)(e1 + ks * 32 + 4);
                half8 af0, af1;
                #pragma unroll
                for (int e = 0; e < 8; ++e) {
                    af0[e] = (_Float16)(lv0[e] * invA0);
                    af1[e] = (_Float16)(lv1[e] * invA1);
                }
                half8 bq0 = *(const half8*)(wb0 + ks * 32);
                half8 bq1 = *(const half8*)(wb1 + ks * 32);
                acc[0][0] = __builtin_amdgcn_mfma_f32_16x16x32_f16(af0, bq0, acc[0][0], 0, 0, 0);
                acc[0][1] = __builtin_amdgcn_mfma_f32_16x16x32_f16(af0, bq1, acc[0][1], 0, 0, 0);
                acc[1][0] = __builtin_amdgcn_mfma_f32_16x16x32_f16(af1, bq0, acc[1][0], 0, 0, 0);
                acc[1][1] = __builtin_amdgcn_mfma_f32_16x16x32_f16(af1, bq1, acc[1][1], 0, 0, 0);
            }
            e0 += 128; e1 += 128; wb0 += 128; wb1 += 128;
        }
    }

    // ---- h-part: K = 512..1536 (8 iterations) ------------------------------
    {
        const _Float16* a0 = pH0;
        const _Float16* a1 = pH1;
        const _Float16* wb0 = pB0 + OO;
        const _Float16* wb1 = pB1 + OO;
        #pragma unroll 1
        for (int it = 0; it < 8; ++it) {
            #pragma unroll
            for (int ks = 0; ks < 4; ++ks) {
                half8 af0 = *(const half8*)(a0 + ks * 32);
                half8 af1 = *(const half8*)(a1 + ks * 32);
                half8 bq0 = *(const half8*)(wb0 + ks * 32);
                half8 bq1 = *(const half8*)(wb1 + ks * 32);
                acc[0][0] = __builtin_amdgcn_mfma_f32_16x16x32_f16(af0, bq0, acc[0][0], 0, 0, 0);
                acc[0][1] = __builtin_amdgcn_mfma_f32_16x16x32_f16(af0, bq1, acc[0][1], 0, 0, 0);
                acc[1][0] = __builtin_amdgcn_mfma_f32_16x16x32_f16(af1, bq0, acc[1][0], 0, 0, 0);
                acc[1][1] = __builtin_amdgcn_mfma_f32_16x16x32_f16(af1, bq1, acc[1][1], 0, 0, 0);
            }
            a0 += 128; a1 += 128; wb0 += 128; wb1 += 128;
        }
    }
    __syncthreads();   // exch overlay reuse

    // exchange preactivations through LDS, stride 133 fp32
    #pragma unroll
    for (int fm = 0; fm < 2; ++fm)
        #pragma unroll
        for (int fn = 0; fn < 2; ++fn)
            #pragma unroll
            for (int r = 0; r < 4; ++r) {
                int row = wm * 32 + fm * 16 + l4 * 4 + r;   // batch-local
                int col = wn * 32 + fn * 16 + l15;          // p-local
                exch[row * 133 + col] = acc[fm][fn][r];
            }
    __syncthreads();

    // cell update: 512 threads, 64 rows x 32 units -> 8 thr/row, 4 units each
    int bl = tid >> 3;
    int b = b0 + bl;
    int jbase = (tid & 7) * 4;
    float cv[4], hv[4], cold[4];
    *(float4*)&cold[0] = *(const float4*)&cst[(size_t)b * HH + pt * 32 + jbase];
    #pragma unroll
    for (int u = 0; u < 4; ++u) {
        int jr = jbase + u;
        float gi = exch[bl * 133 +      jr] + bias_p[p0 +      jr];
        float gf = exch[bl * 133 + 32 + jr] + bias_p[p0 + 32 + jr];
        float gg = exch[bl * 133 + 64 + jr] + bias_p[p0 + 64 + jr];
        float go = exch[bl * 133 + 96 + jr] + bias_p[p0 + 96 + jr];
        float iv = 1.f / (1.f + expf(-gi));
        float fv = 1.f / (1.f + expf(-gf));
        float gv = tanhf(gg);
        float ov = 1.f / (1.f + expf(-go));
        float cnew = fv * cold[u] + iv * gv;
        cv[u] = cnew;
        hv[u] = ov * tanhf(cnew);
    }
    *(float4*)&cst[(size_t)b * HH + pt * 32 + jbase] = *(const float4*)&cv[0];
    half4 hh;
    #pragma unroll
    for (int u = 0; u < 4; ++u) hh[u] = (_Float16)hv[u];
    *(half4*)&h_out[(size_t)b * HH + pt * 32 + jbase] = hh;
}

// ---------------------------------------------------------------------------
// logits_exp: direct-to-register fragment GEMM, 32b x 32o per block,
// 256 threads = 4 waves (2 batch x 2 o), each wave 16x16. No LDS, no
// K-loop barriers. Epilogue: e = expf(acc + b_out) once per element, store e
// and per-(block,wave) partial row sums Spart[b][ot*2+wn].
// ---------------------------------------------------------------------------
__global__ __launch_bounds__(256) void logits_exp(
    const _Float16* __restrict__ hb,      // [B][H]
    const _Float16* __restrict__ Wout16,  // [O][H]
    const float* __restrict__ b_out,
    float* __restrict__ ebuf,             // [B][O] exp(logits)
    float* __restrict__ Spart)            // [B][32]
{
    const int ot = blockIdx.x;
    const int o0 = ot * 32, b0 = blockIdx.y * 32;
    const int tid = threadIdx.x;
    const int l = tid & 63, w = tid >> 6;
    const int wm = w & 1, wn = w >> 1;      // 2(b) x 2(o)
    const int l15 = l & 15, l4 = l >> 4;

    f32x4 acc = (f32x4){0.f, 0.f, 0.f, 0.f};

    const _Float16* pA = &hb[(size_t)(b0 + wm * 16 + l15) * HH + l4 * 8];
    const _Float16* pB = &Wout16[(size_t)(o0 + wn * 16 + l15) * HH + l4 * 8];

    #pragma unroll 1
    for (int it = 0; it < 8; ++it) {
        #pragma unroll
        for (int ks = 0; ks < 4; ++ks) {
            half8 a  = *(const half8*)(pA + ks * 32);
            half8 bq = *(const half8*)(pB + ks * 32);
            acc = __builtin_amdgcn_mfma_f32_16x16x32_f16(a, bq, acc, 0, 0, 0);
        }
        pA += 128; pB += 128;
    }

    // epilogue: e = exp(logit), store + partial row sums
    float ps[4];
    #pragma unroll
    for (int r = 0; r < 4; ++r) {
        int row = b0 + wm * 16 + l4 * 4 + r;
        int col = o0 + wn * 16 + l15;
        float e = expf(acc[r] + b_out[col]);
        ebuf[(size_t)row * OO + col] = e;
        ps[r] = e;
    }
    #pragma unroll
    for (int r = 0; r < 4; ++r) {
        #pragma unroll
        for (int off = 1; off < 16; off <<= 1)
            ps[r] += __shfl_xor(ps[r], off, 64);
    }
    if (l15 == 0) {
        #pragma unroll
        for (int r = 0; r < 4; ++r) {
            int row = b0 + wm * 16 + l4 * 4 + r;
            Spart[(size_t)row * 32 + ot * 2 + wn] = ps[r];
        }
    }
}

// ---------------------------------------------------------------------------
// softmax_out: final slice (slice 0) from ebuf/Spart of step TT-1.
// ---------------------------------------------------------------------------
__global__ __launch_bounds__(256) void softmax_out(
    const float* __restrict__ ebuf, const float* __restrict__ Spart,
    float* __restrict__ out_slice)
{
    const int w = threadIdx.x >> 6, l = threadIdx.x & 63;
    const int b = blockIdx.x * 4 + w;
    const float* sp = &Spart[(size_t)b * 32];
    float s = 0.f;
    #pragma unroll
    for (int u = 0; u < 32; ++u) s += sp[u];
    float inv = 1.f / s;
    float v[8], y[8];
    *(float4*)&v[0] = *(const float4*)&ebuf[(size_t)b * OO + l * 8];
    *(float4*)&v[4] = *(const float4*)&ebuf[(size_t)b * OO + l * 8 + 4];
    #pragma unroll
    for (int u = 0; u < 8; ++u) y[u] = v[u] * inv;
    *(float4*)&out_slice[(size_t)b * OO + l * 8]     = *(const float4*)&y[0];
    *(float4*)&out_slice[(size_t)b * OO + l * 8 + 4] = *(const float4*)&y[4];
}

// ---------------------------------------------------------------------------
extern "C" void kernel_launch(void* const* d_in, const int* in_sizes, int n_in,
                              void* d_out, int out_size, void* d_ws, size_t ws_size,
                              hipStream_t stream)
{
    const float* h0    = (const float*)d_in[0];
    const float* c0    = (const float*)d_in[1];
    const float* W_ih  = (const float*)d_in[2];
    const float* W_hh  = (const float*)d_in[3];
    const float* b_ih  = (const float*)d_in[4];
    const float* b_hh  = (const float*)d_in[5];
    const float* W_out = (const float*)d_in[6];
    const float* b_out = (const float*)d_in[7];
    float* out = (float*)d_out;

    char* wsb = (char*)d_ws;
    _Float16* Wcat   = (_Float16*)wsb;                 wsb += (size_t)G4H * KC * 2;
    _Float16* Wout16 = (_Float16*)wsb;                 wsb += (size_t)OO * HH * 2;
    float*    bias_p = (float*)wsb;                    wsb += (size_t)G4H * 4;
    _Float16* hb0    = (_Float16*)wsb;                 wsb += (size_t)BB * HH * 2;
    _Float16* hb1    = (_Float16*)wsb;                 wsb += (size_t)BB * HH * 2;
    float*    cst    = (float*)wsb;                    wsb += (size_t)BB * HH * 4;
    float*    ebuf   = (float*)wsb;                    wsb += (size_t)BB * OO * 4;
    float*    Spart  = (float*)wsb;                    wsb += (size_t)BB * 32 * 4;

    conv_wcat<<<dim3(KC / 256, G4H), 256, 0, stream>>>(W_ih, W_hh, Wcat);
    conv_wout<<<dim3(HH / 256, OO), 256, 0, stream>>>(W_out, Wout16);
    prep_misc<<<512, 256, 0, stream>>>(b_ih, b_hh, h0, c0, bias_p, hb0, cst);

    for (int t = 0; t < TT; ++t) {
        _Float16* hin  = (t & 1) ? hb1 : hb0;
        _Float16* hout = (t & 1) ? hb0 : hb1;
        float* oslice = (t == 0) ? out : out + (size_t)(TT - t) * BB * OO;
        gates_sf2<<<dim3(32, 8), 512, 0, stream>>>(
            ebuf, Spart, hin, hout, cst, Wcat, bias_p, oslice, (t == 0) ? 1 : 0);
        logits_exp<<<dim3(16, 16), 256, 0, stream>>>(hout, Wout16, b_out, ebuf, Spart);
    }
    // final: slice 0 from ebuf/Spart of step TT-1
    softmax_out<<<128, 256, 0, stream>>>(ebuf, Spart, out);
}